// Round 1
// baseline (188.762 us; speedup 1.0000x reference)
//
#include <hip/hip_runtime.h>

#define GSZ 7
#define NWIN 49      // GS*GS
#define NHEADS 8
#define DHEAD 32     // C / heads
#define CCH 256      // C
#define QPAD 36      // padded LDS row stride for q / out staging (16B-aligned, breaks bank conflicts)

// Kernel A: pos MLP table, (169, 8) fp32. biases[idx] = (idx/13 - 6, idx%13 - 6);
// pos = relu(biases @ W1 + b1) @ W2 + b2
__global__ void pos_bias_kernel(const float* __restrict__ W1,   // (2,64)
                                const float* __restrict__ b1,   // (64)
                                const float* __restrict__ W2,   // (64,8)
                                const float* __restrict__ b2,   // (8)
                                float* __restrict__ pos) {      // (169,8)
    int idx = blockIdx.x * blockDim.x + threadIdx.x;
    if (idx >= 169) return;
    float bh = (float)(idx / 13) - 6.0f;
    float bw = (float)(idx % 13) - 6.0f;
    float outv[NHEADS];
#pragma unroll
    for (int t = 0; t < NHEADS; ++t) outv[t] = b2[t];
    for (int u = 0; u < 64; ++u) {
        float hv = fmaf(bh, W1[u], fmaf(bw, W1[64 + u], b1[u]));
        hv = fmaxf(hv, 0.0f);
#pragma unroll
        for (int t = 0; t < NHEADS; ++t) outv[t] = fmaf(hv, W2[u * NHEADS + t], outv[t]);
    }
#pragma unroll
    for (int t = 0; t < NHEADS; ++t) pos[idx * NHEADS + t] = outv[t];
}

// Kernel B: one 64-thread block per (batch-window, head).
__global__ __launch_bounds__(64) void attn_kernel(
    const float* __restrict__ q, const float* __restrict__ k,
    const float* __restrict__ v, const float* __restrict__ pos,
    float* __restrict__ out) {
    const int blk = blockIdx.x;
    const int b = blk >> 3;   // window index
    const int h = blk & 7;    // head
    const int tid = threadIdx.x;

    __shared__ float lds_k[NWIN * DHEAD];
    __shared__ float lds_v[NWIN * DHEAD];
    __shared__ float lds_q[NWIN * QPAD];   // also reused as output staging

    const size_t base = (size_t)b * (NWIN * CCH) + (size_t)h * DHEAD;

    // Cooperative staging: 49 rows x 8 float4 per tensor. Rows are 128B
    // contiguous segments (coalesced within a row).
#pragma unroll
    for (int it = 0; it < 7; ++it) {
        int idx = tid + it * 64;
        if (idx < NWIN * 8) {
            int row = idx >> 3, c4 = idx & 7;
            size_t g = base + (size_t)row * CCH + (size_t)(c4 * 4);
            *(float4*)&lds_q[row * QPAD + c4 * 4] = *(const float4*)(q + g);
            *(float4*)&lds_k[row * DHEAD + c4 * 4] = *(const float4*)(k + g);
            *(float4*)&lds_v[row * DHEAD + c4 * 4] = *(const float4*)(v + g);
        }
    }
    __syncthreads();

    if (tid < NWIN) {
        const int i = tid;
        // q row -> registers (padded stride: ~8-way conflict once, negligible)
        float qr[DHEAD];
#pragma unroll
        for (int kk = 0; kk < DHEAD; ++kk) qr[kk] = lds_q[i * QPAD + kk];

        const int ih = i / 7, iw = i % 7;
        const float scale = 0.17677669529663687f;   // 32^-0.5
        float p[NWIN];
#pragma unroll
        for (int j = 0; j < NWIN; ++j) {
            float s = 0.0f;
#pragma unroll
            for (int kk = 0; kk < DHEAD; ++kk)
                s = fmaf(qr[kk], lds_k[j * DHEAD + kk], s);   // broadcast read
            const int rel = (ih - (j / 7) + 6) * 13 + (iw - (j % 7) + 6); // j consts fold
            p[j] = fmaf(s, scale, pos[rel * NHEADS + h]);      // bias via L1-hot table
        }
        // softmax (row-serial; deferred normalization)
        float m = p[0];
#pragma unroll
        for (int j = 1; j < NWIN; ++j) m = fmaxf(m, p[j]);
        float sum = 0.0f;
#pragma unroll
        for (int j = 0; j < NWIN; ++j) { p[j] = __expf(p[j] - m); sum += p[j]; }
        const float inv = 1.0f / sum;

        float acc[DHEAD];
#pragma unroll
        for (int dd = 0; dd < DHEAD; ++dd) acc[dd] = 0.0f;
#pragma unroll
        for (int j = 0; j < NWIN; ++j) {
            const float pj = p[j];
#pragma unroll
            for (int dd = 0; dd < DHEAD; ++dd)
                acc[dd] = fmaf(pj, lds_v[j * DHEAD + dd], acc[dd]);  // broadcast read
        }
#pragma unroll
        for (int dd = 0; dd < DHEAD; ++dd) lds_q[i * QPAD + dd] = acc[dd] * inv;
    }
    __syncthreads();

    // Coalesced float4 store via LDS staging
#pragma unroll
    for (int it = 0; it < 7; ++it) {
        int idx = tid + it * 64;
        if (idx < NWIN * 8) {
            int row = idx >> 3, c4 = idx & 7;
            *(float4*)(out + base + (size_t)row * CCH + (size_t)(c4 * 4)) =
                *(const float4*)&lds_q[row * QPAD + c4 * 4];
        }
    }
}

extern "C" void kernel_launch(void* const* d_in, const int* in_sizes, int n_in,
                              void* d_out, int out_size, void* d_ws, size_t ws_size,
                              hipStream_t stream) {
    const float* q  = (const float*)d_in[0];
    const float* k  = (const float*)d_in[1];
    const float* v  = (const float*)d_in[2];
    const float* W1 = (const float*)d_in[3];
    const float* b1 = (const float*)d_in[4];
    const float* W2 = (const float*)d_in[5];
    const float* b2 = (const float*)d_in[6];
    // d_in[7], d_in[8] = H, W — for N==49 both reference branches are identical.

    float* pos = (float*)d_ws;          // 169*8 fp32 = 5408 B
    float* out = (float*)d_out;

    const int B = in_sizes[0] / (NWIN * CCH);   // 2048

    pos_bias_kernel<<<1, 192, 0, stream>>>(W1, b1, W2, b2, pos);
    attn_kernel<<<B * NHEADS, 64, 0, stream>>>(q, k, v, pos, out);
}

// Round 2
// 132.969 us; speedup vs baseline: 1.4196x; 1.4196x over previous
//
#include <hip/hip_runtime.h>

typedef __attribute__((ext_vector_type(8))) short bf16x8;
typedef __attribute__((ext_vector_type(4))) float f32x4;

#define NWIN 49
#define NH 8
#define DH 32
#define CCH 256
#define LROW 40   // ushort stride, Q/K rows (80B: 16B-aligned, conflict-free frag reads)
#define VROW 72   // ushort stride, Vt and P rows (144B: 16B-aligned)

__device__ __forceinline__ ushort bf16_rne(float x) {
    unsigned u = __float_as_uint(x);
    return (ushort)((u + 0x7FFFu + ((u >> 16) & 1u)) >> 16);
}
__device__ __forceinline__ float bf16_to_f(ushort h) {
    return __uint_as_float(((unsigned)h) << 16);
}

// --- Kernel A: pos MLP table, (169, 8) fp32 ---
__global__ void pos_mlp_kernel(const float* __restrict__ W1, const float* __restrict__ b1,
                               const float* __restrict__ W2, const float* __restrict__ b2,
                               float* __restrict__ pos) {
    int idx = blockIdx.x * blockDim.x + threadIdx.x;
    if (idx >= 169) return;
    float bh = (float)(idx / 13) - 6.0f;
    float bw = (float)(idx % 13) - 6.0f;
    float outv[NH];
#pragma unroll
    for (int t = 0; t < NH; ++t) outv[t] = b2[t];
    for (int u = 0; u < 64; ++u) {
        float hv = fmaf(bh, W1[u], fmaf(bw, W1[64 + u], b1[u]));
        hv = fmaxf(hv, 0.0f);
#pragma unroll
        for (int t = 0; t < NH; ++t) outv[t] = fmaf(hv, W2[u * NH + t], outv[t]);
    }
#pragma unroll
    for (int t = 0; t < NH; ++t) pos[idx * NH + t] = outv[t];
}

// --- Kernel B: bias in S^T MFMA C/D fragment layout, with -1e30 masking for j>=49.
// bfrag[((h*4 + jt)*4 + it)*256 + lane*4 + r] = bias(query i = it*16+(lane&15),
//                                                    key   j = jt*16+(lane>>4)*4+r)
__global__ void bias_frag_kernel(const float* __restrict__ pos, float* __restrict__ bfrag) {
    int blk = blockIdx.x;           // ((h*4 + jt)*4 + it), 128 blocks
    int it = blk & 3, jt = (blk >> 2) & 3, h = blk >> 4;
    int lane = threadIdx.x;
    int g = lane >> 4, l15 = lane & 15;
    int i = it * 16 + l15;
    float4 v;
    float* vp = (float*)&v;
#pragma unroll
    for (int r = 0; r < 4; ++r) {
        int j = jt * 16 + g * 4 + r;
        float val;
        if (j >= NWIN) val = -1e30f;                 // mask padded keys
        else if (i >= NWIN) val = 0.0f;              // padded queries: finite, unused
        else {
            int rel = (i / 7 - j / 7 + 6) * 13 + (i % 7 - j % 7 + 6);
            val = pos[rel * NH + h];
        }
        vp[r] = val;
    }
    *(float4*)(bfrag + (size_t)blk * 256 + lane * 4) = v;
}

// --- Kernel C: one 64-thread wave per (window, head). MFMA attention. ---
__global__ __launch_bounds__(64) void attn_kernel(
    const float* __restrict__ q, const float* __restrict__ k,
    const float* __restrict__ v, const float* __restrict__ bfrag,
    float* __restrict__ out) {
    // pool: qh[64*40] ql[64*40] kh[64*40] kl[64*40] vt[32*72]  (25088 B)
    __shared__ __align__(16) ushort pool[12544];
    ushort* qh = pool;
    ushort* ql = pool + 2560;
    ushort* kh = pool + 5120;
    ushort* kl = pool + 7680;
    ushort* vt = pool + 10240;      // [32][72]
    ushort* plds = pool;            // [64][72] = 4608 <= 5120 (reuses dead qh+ql)

    const int blk = blockIdx.x;
    const int b = blk >> 3, h = blk & 7;
    const int lane = threadIdx.x;
    const int g = lane >> 4, l15 = lane & 15;
    const size_t base = (size_t)b * (NWIN * CCH) + h * DH;

    // ---- stage Q,K (bf16 hi+lo) and V^T (bf16), pad rows zeroed ----
#pragma unroll
    for (int itr = 0; itr < 8; ++itr) {
        int idx = lane + itr * 64;            // 0..511 -> (row 0..63, c4 0..7)
        int row = idx >> 3, c4 = idx & 7;
        float4 qv = {0,0,0,0}, kv = {0,0,0,0}, vv = {0,0,0,0};
        if (row < NWIN) {
            size_t gaddr = base + (size_t)row * CCH + c4 * 4;
            qv = *(const float4*)(q + gaddr);
            kv = *(const float4*)(k + gaddr);
            vv = *(const float4*)(v + gaddr);
        }
        ushort4 qhi, qlo, khi, klo;
        qhi.x = bf16_rne(qv.x); qlo.x = bf16_rne(qv.x - bf16_to_f(qhi.x));
        qhi.y = bf16_rne(qv.y); qlo.y = bf16_rne(qv.y - bf16_to_f(qhi.y));
        qhi.z = bf16_rne(qv.z); qlo.z = bf16_rne(qv.z - bf16_to_f(qhi.z));
        qhi.w = bf16_rne(qv.w); qlo.w = bf16_rne(qv.w - bf16_to_f(qhi.w));
        khi.x = bf16_rne(kv.x); klo.x = bf16_rne(kv.x - bf16_to_f(khi.x));
        khi.y = bf16_rne(kv.y); klo.y = bf16_rne(kv.y - bf16_to_f(khi.y));
        khi.z = bf16_rne(kv.z); klo.z = bf16_rne(kv.z - bf16_to_f(khi.z));
        khi.w = bf16_rne(kv.w); klo.w = bf16_rne(kv.w - bf16_to_f(khi.w));
        *(ushort4*)&qh[row * LROW + c4 * 4] = qhi;
        *(ushort4*)&ql[row * LROW + c4 * 4] = qlo;
        *(ushort4*)&kh[row * LROW + c4 * 4] = khi;
        *(ushort4*)&kl[row * LROW + c4 * 4] = klo;
        vt[(c4 * 4 + 0) * VROW + row] = bf16_rne(vv.x);
        vt[(c4 * 4 + 1) * VROW + row] = bf16_rne(vv.y);
        vt[(c4 * 4 + 2) * VROW + row] = bf16_rne(vv.z);
        vt[(c4 * 4 + 3) * VROW + row] = bf16_rne(vv.w);
    }
    __syncthreads();

    // ---- QK^T (swapped): acc[jt][it] = S^T tile, bf16x3 for fp32-accurate logits ----
    bf16x8 kah[4], kal[4], qbh[4], qbl[4];
#pragma unroll
    for (int t = 0; t < 4; ++t) {
        kah[t] = *(const bf16x8*)&kh[(t * 16 + l15) * LROW + g * 8];
        kal[t] = *(const bf16x8*)&kl[(t * 16 + l15) * LROW + g * 8];
        qbh[t] = *(const bf16x8*)&qh[(t * 16 + l15) * LROW + g * 8];
        qbl[t] = *(const bf16x8*)&ql[(t * 16 + l15) * LROW + g * 8];
    }
    f32x4 acc[4][4];
#pragma unroll
    for (int jt = 0; jt < 4; ++jt)
#pragma unroll
        for (int it = 0; it < 4; ++it)
            acc[jt][it] = (f32x4){0.f, 0.f, 0.f, 0.f};
#pragma unroll
    for (int jt = 0; jt < 4; ++jt)
#pragma unroll
        for (int it = 0; it < 4; ++it) {
            acc[jt][it] = __builtin_amdgcn_mfma_f32_16x16x32_bf16(kah[jt], qbh[it], acc[jt][it], 0, 0, 0);
            acc[jt][it] = __builtin_amdgcn_mfma_f32_16x16x32_bf16(kah[jt], qbl[it], acc[jt][it], 0, 0, 0);
            acc[jt][it] = __builtin_amdgcn_mfma_f32_16x16x32_bf16(kal[jt], qbh[it], acc[jt][it], 0, 0, 0);
        }

    // ---- scale + bias (fragment-layout table, L2-hot) ----
    const float scale = 0.17677669529663687f;   // 32^-0.5
#pragma unroll
    for (int jt = 0; jt < 4; ++jt)
#pragma unroll
        for (int it = 0; it < 4; ++it) {
            f32x4 bb = *(const f32x4*)(bfrag + (size_t)(((h * 4 + jt) * 4 + it)) * 256 + lane * 4);
#pragma unroll
            for (int r = 0; r < 4; ++r)
                acc[jt][it][r] = fmaf(acc[jt][it][r], scale, bb[r]);
        }

    // ---- softmax over j (rows of S^T) per column i = it*16 + l15 ----
#pragma unroll
    for (int it = 0; it < 4; ++it) {
        float m = -1e30f;
#pragma unroll
        for (int jt = 0; jt < 4; ++jt)
#pragma unroll
            for (int r = 0; r < 4; ++r) m = fmaxf(m, acc[jt][it][r]);
        m = fmaxf(m, __shfl_xor(m, 16));
        m = fmaxf(m, __shfl_xor(m, 32));
        float s = 0.0f;
#pragma unroll
        for (int jt = 0; jt < 4; ++jt)
#pragma unroll
            for (int r = 0; r < 4; ++r) {
                float p = __expf(acc[jt][it][r] - m);
                acc[jt][it][r] = p;
                s += p;
            }
        s += __shfl_xor(s, 16);
        s += __shfl_xor(s, 32);
        float inv = 1.0f / s;
#pragma unroll
        for (int jt = 0; jt < 4; ++jt)
#pragma unroll
            for (int r = 0; r < 4; ++r) acc[jt][it][r] *= inv;
    }

    // ---- P -> LDS bf16 [i][j] (reuses dead Q buffers; single wave => no barrier) ----
#pragma unroll
    for (int jt = 0; jt < 4; ++jt)
#pragma unroll
        for (int it = 0; it < 4; ++it) {
            ushort4 pw;
            pw.x = bf16_rne(acc[jt][it][0]);
            pw.y = bf16_rne(acc[jt][it][1]);
            pw.z = bf16_rne(acc[jt][it][2]);
            pw.w = bf16_rne(acc[jt][it][3]);
            *(ushort4*)&plds[(it * 16 + l15) * VROW + jt * 16 + g * 4] = pw;
        }

    // ---- PV: out[i][d] = sum_j P[i][j] V[j][d] ----
    f32x4 oacc[4][2];
#pragma unroll
    for (int mt = 0; mt < 4; ++mt)
#pragma unroll
        for (int nt = 0; nt < 2; ++nt) oacc[mt][nt] = (f32x4){0.f, 0.f, 0.f, 0.f};
#pragma unroll
    for (int ks = 0; ks < 2; ++ks) {
        bf16x8 pa[4], bv[2];
#pragma unroll
        for (int mt = 0; mt < 4; ++mt)
            pa[mt] = *(const bf16x8*)&plds[(mt * 16 + l15) * VROW + ks * 32 + g * 8];
#pragma unroll
        for (int nt = 0; nt < 2; ++nt)
            bv[nt] = *(const bf16x8*)&vt[(nt * 16 + l15) * VROW + ks * 32 + g * 8];
#pragma unroll
        for (int mt = 0; mt < 4; ++mt)
#pragma unroll
            for (int nt = 0; nt < 2; ++nt)
                oacc[mt][nt] = __builtin_amdgcn_mfma_f32_16x16x32_bf16(pa[mt], bv[nt], oacc[mt][nt], 0, 0, 0);
    }

    // ---- store (coalesced: lanes l15 -> consecutive d) ----
#pragma unroll
    for (int mt = 0; mt < 4; ++mt)
#pragma unroll
        for (int r = 0; r < 4; ++r) {
            int i = mt * 16 + g * 4 + r;
            if (i < NWIN) {
#pragma unroll
                for (int nt = 0; nt < 2; ++nt)
                    out[base + (size_t)i * CCH + nt * 16 + l15] = oacc[mt][nt][r];
            }
        }
}

extern "C" void kernel_launch(void* const* d_in, const int* in_sizes, int n_in,
                              void* d_out, int out_size, void* d_ws, size_t ws_size,
                              hipStream_t stream) {
    const float* q  = (const float*)d_in[0];
    const float* k  = (const float*)d_in[1];
    const float* v  = (const float*)d_in[2];
    const float* W1 = (const float*)d_in[3];
    const float* b1 = (const float*)d_in[4];
    const float* W2 = (const float*)d_in[5];
    const float* b2 = (const float*)d_in[6];

    float* pos   = (float*)d_ws;                       // 169*8 fp32
    float* bfrag = (float*)((char*)d_ws + 8192);       // 8*4*4*64*4 fp32 = 131072 B
    float* out   = (float*)d_out;

    const int B = in_sizes[0] / (NWIN * CCH);          // 2048

    pos_mlp_kernel<<<1, 192, 0, stream>>>(W1, b1, W2, b2, pos);
    bias_frag_kernel<<<128, 64, 0, stream>>>(pos, bfrag);
    attn_kernel<<<B * NH, 64, 0, stream>>>(q, k, v, bfrag, out);
}